// Round 23
// baseline (1068.111 us; speedup 1.0000x reference)
//
#include <hip/hip_runtime.h>
#include <math.h>

#define Bq 4
#define Tt 2048
#define Dd 512
#define Hh 8
#define Ll 4
#define HIDN 2048
#define DHd 64
#define BT (Bq*Tt)                 // 8192
#define BTD ((size_t)BT*Dd)        // 4194304

typedef __attribute__((ext_vector_type(8))) __bf16 bf16x8;
typedef __attribute__((ext_vector_type(4))) __bf16 bf16x4;
typedef __attribute__((ext_vector_type(2))) __bf16 bf16x2;
typedef __attribute__((ext_vector_type(4))) float f32x4;

static __device__ __forceinline__ int is_sep(int t) {
    const unsigned long long w0 = 0xFC00FFFF00002600ULL;
    const unsigned long long w1 = 0x7800000078000001ULL;
    if (t < 64)  return (int)((w0 >> t) & 1ULL);
    if (t < 128) return (int)((w1 >> (t - 64)) & 1ULL);
    return 0;
}

static __device__ __forceinline__ void gload16(const void* g, void* l) {
    __builtin_amdgcn_global_load_lds(
        (const __attribute__((address_space(1))) void*)g,
        (__attribute__((address_space(3))) void*)l, 16, 0, 0);
}

__global__ void embed_kernel(const int* __restrict__ tokens, const float* __restrict__ embed,
                             float* __restrict__ x) {
    size_t idx = (size_t)blockIdx.x * blockDim.x + threadIdx.x;
    if (idx >= BTD / 4) return;
    size_t row = idx >> 7;
    int tk = tokens[row];
    tk = tk < 0 ? 0 : (tk > 255 ? 255 : tk);
    const float4* src = (const float4*)(embed + (size_t)tk * Dd);
    ((float4*)x)[idx] = src[idx & 127];
}

__global__ void rope_table_kernel(float* __restrict__ cosb, float* __restrict__ sinb) {
    int idx = blockIdx.x * blockDim.x + threadIdx.x;
    if (idx >= Tt * 32) return;
    int t = idx >> 5, j = idx & 31;
    float inv = powf(10000.0f, -(2.0f * j) / 64.0f);
    float ang = (float)t * inv;
    cosb[idx] = cosf(ang);
    sinb[idx] = sinf(ang);
}

// fused fp32->bf16 conversion for wo|w1|w3|w2 (contiguous dest arena)
__global__ void cvt_w_kernel(const float* __restrict__ wo, const float* __restrict__ w1,
                             const float* __restrict__ w3, const float* __restrict__ w2,
                             __bf16* __restrict__ dst) {
    int i = blockIdx.x * blockDim.x + threadIdx.x;   // 1703936 groups of 8
    if (i >= 1703936) return;
    const float* src;
    if (i < 131072)       src = wo + (size_t)i * 8;
    else if (i < 655360)  src = w1 + (size_t)(i - 131072) * 8;
    else if (i < 1179648) src = w3 + (size_t)(i - 655360) * 8;
    else                  src = w2 + (size_t)(i - 1179648) * 8;
    float4 a = *(const float4*)src;
    float4 b = *(const float4*)(src + 4);
    bf16x8 o8;
    o8[0] = (__bf16)a.x; o8[1] = (__bf16)a.y; o8[2] = (__bf16)a.z; o8[3] = (__bf16)a.w;
    o8[4] = (__bf16)b.x; o8[5] = (__bf16)b.y; o8[6] = (__bf16)b.z; o8[7] = (__bf16)b.w;
    *(bf16x8*)(dst + (size_t)i * 8) = o8;
}

// concat wq/wk/wv -> wqkv[L][1536][512] bf16
__global__ void cvt_qkv_kernel(const float* __restrict__ wq, const float* __restrict__ wk,
                               const float* __restrict__ wv, __bf16* __restrict__ out) {
    int i = blockIdx.x * blockDim.x + threadIdx.x;   // 393216
    if (i >= 393216) return;
    int l = i / 98304;
    int r = i - l * 98304;
    int t = r >> 15;             // /32768
    int pos8 = r & 32767;
    const float* src = (t == 0 ? wq : (t == 1 ? wk : wv)) + (size_t)l * 262144 + (size_t)pos8 * 8;
    float4 a = *(const float4*)src;
    float4 b = *(const float4*)(src + 4);
    bf16x8 o8;
    o8[0] = (__bf16)a.x; o8[1] = (__bf16)a.y; o8[2] = (__bf16)a.z; o8[3] = (__bf16)a.w;
    o8[4] = (__bf16)b.x; o8[5] = (__bf16)b.y; o8[6] = (__bf16)b.z; o8[7] = (__bf16)b.w;
    *(bf16x8*)(out + (size_t)i * 8) = o8;
}

// fp32 in, bf16 out (layer norms)
__global__ void rmsnorm_bf16_kernel(const float* __restrict__ x, const float* __restrict__ w,
                                    __bf16* __restrict__ y) {
    int row = blockIdx.x * 4 + (threadIdx.x >> 6);
    int lane = threadIdx.x & 63;
    const float* xr = x + (size_t)row * Dd + lane * 8;
    float4 a = *(const float4*)xr;
    float4 b = *(const float4*)(xr + 4);
    float ss = a.x * a.x + a.y * a.y + a.z * a.z + a.w * a.w
             + b.x * b.x + b.y * b.y + b.z * b.z + b.w * b.w;
    #pragma unroll
    for (int off = 1; off < 64; off <<= 1) ss += __shfl_xor(ss, off);
    float scale = rsqrtf(ss * (1.0f / Dd) + 1e-6f);
    const float* wr = w + lane * 8;
    float4 wa = *(const float4*)wr;
    float4 wb = *(const float4*)(wr + 4);
    bf16x8 o;
    o[0] = (__bf16)(a.x * scale * wa.x); o[1] = (__bf16)(a.y * scale * wa.y);
    o[2] = (__bf16)(a.z * scale * wa.z); o[3] = (__bf16)(a.w * scale * wa.w);
    o[4] = (__bf16)(b.x * scale * wb.x); o[5] = (__bf16)(b.y * scale * wb.y);
    o[6] = (__bf16)(b.z * scale * wb.z); o[7] = (__bf16)(b.w * scale * wb.w);
    *(bf16x8*)(y + (size_t)row * Dd + lane * 8) = o;
}

// Final RMSNorm, in-place on x.
__global__ void rmsnorm_inplace_kernel(float* __restrict__ x, const float* __restrict__ w) {
    int row = blockIdx.x * 4 + (threadIdx.x >> 6);
    int lane = threadIdx.x & 63;
    float* xr = x + (size_t)row * Dd + lane * 8;
    float4 a = *(const float4*)xr;
    float4 b = *(const float4*)(xr + 4);
    float ss = a.x * a.x + a.y * a.y + a.z * a.z + a.w * a.w
             + b.x * b.x + b.y * b.y + b.z * b.z + b.w * b.w;
    #pragma unroll
    for (int off = 1; off < 64; off <<= 1) ss += __shfl_xor(ss, off);
    float scale = rsqrtf(ss * (1.0f / Dd) + 1e-6f);
    const float* wr = w + lane * 8;
    float4 wa = *(const float4*)wr;
    float4 wb = *(const float4*)(wr + 4);
    *(float4*)xr = make_float4(a.x * scale * wa.x, a.y * scale * wa.y,
                               a.z * scale * wa.z, a.w * scale * wa.w);
    *(float4*)(xr + 4) = make_float4(b.x * scale * wb.x, b.y * scale * wb.y,
                                     b.z * scale * wb.z, b.w * scale * wb.w);
}

// C = A(bf16) @ Bw(bf16)^T. 128x128 tile, BK=32, double-buffered gload_lds.
// EPI 0: bf16 out stride N. EPI 1: f32 out + f32 residual.
// EPI 2: bf16 QKV split + fused RoPE on q/k cols (q also scaled 0.125*log2e).
template<int EPI>
__global__ __launch_bounds__(256) void gemm_bt_mfma(
    const __bf16* __restrict__ A, const __bf16* __restrict__ Bw,
    const float* __restrict__ res, void* __restrict__ Cout,
    int N, int K,
    const float* __restrict__ cosb, const float* __restrict__ sinb) {
    __shared__ __align__(16) __bf16 lds[2][2][128 * 32];
    const int tid = threadIdx.x;
    const int w = tid >> 6, lane = tid & 63;
    const int l15 = lane & 15, g4 = lane >> 4;
    const int wr = w >> 1, wc = w & 1;
    const int bm = blockIdx.y * 128, bn = blockIdx.x * 128;
    const int lrow = lane >> 2, lc8 = (lane & 3) * 8;
    const int chunk0 = w * 2;

    f32x4 acc[4][4];
    #pragma unroll
    for (int m = 0; m < 4; m++)
        #pragma unroll
        for (int n = 0; n < 4; n++) acc[m][n] = (f32x4){0.f, 0.f, 0.f, 0.f};

    auto stage = [&](int buf, int k0) {
        #pragma unroll
        for (int c = 0; c < 2; c++) {
            int chunk = chunk0 + c;
            const __bf16* ga = A + (size_t)(bm + chunk * 16 + lrow) * K + k0 + lc8;
            gload16(ga, &lds[buf][0][chunk * 512]);
            const __bf16* gb = Bw + (size_t)(bn + chunk * 16 + lrow) * K + k0 + lc8;
            gload16(gb, &lds[buf][1][chunk * 512]);
        }
    };

    stage(0, 0);
    __syncthreads();
    const int NT = K >> 5;
    int cur = 0;
    for (int t = 0; t < NT; t++) {
        if (t + 1 < NT) stage(cur ^ 1, (t + 1) << 5);
        const __bf16* Al = &lds[cur][0][0];
        const __bf16* Bl = &lds[cur][1][0];
        bf16x8 af[4], bfr[4];
        #pragma unroll
        for (int m = 0; m < 4; m++)
            af[m] = *(const bf16x8*)&Al[(wr * 64 + m * 16 + l15) * 32 + g4 * 8];
        #pragma unroll
        for (int n = 0; n < 4; n++)
            bfr[n] = *(const bf16x8*)&Bl[(wc * 64 + n * 16 + l15) * 32 + g4 * 8];
        #pragma unroll
        for (int m = 0; m < 4; m++)
            #pragma unroll
            for (int n = 0; n < 4; n++)
                acc[m][n] = __builtin_amdgcn_mfma_f32_16x16x32_bf16(af[m], bfr[n], acc[m][n], 0, 0, 0);
        __syncthreads();
        cur ^= 1;
    }

    #pragma unroll
    for (int m = 0; m < 4; m++)
        #pragma unroll
        for (int n = 0; n < 4; n++)
            #pragma unroll
            for (int r = 0; r < 4; r++) {
                size_t row = bm + wr * 64 + m * 16 + g4 * 4 + r;
                int col = bn + wc * 64 + n * 16 + l15;
                if (EPI == 0) {
                    ((__bf16*)Cout)[row * N + col] = (__bf16)acc[m][n][r];
                } else if (EPI == 1) {
                    ((float*)Cout)[row * N + col] = acc[m][n][r] + res[row * N + col];
                } else {
                    float vv = acc[m][n][r];
                    float vp = __shfl_xor(vv, 1);   // rope pair partner (col^1)
                    if (col < 1024) {               // q or k: apply RoPE (uniform per n)
                        int trow = (int)(row & (Tt - 1));
                        int p = (col & 63) >> 1;
                        float c = cosb[trow * 32 + p];
                        float s = sinb[trow * 32 + p];
                        float x1 = (col & 1) ? vp : vv;
                        float x2 = (col & 1) ? vv : vp;
                        float rot = (col & 1) ? (x1 * s + x2 * c) : (x1 * c - x2 * s);
                        if (col < 512) rot *= 0.18033688011112043f;   // 0.125*log2(e)
                        vv = rot;
                    }
                    ((__bf16*)Cout)[(size_t)(col >> 9) * BTD + row * 512 + (col & 511)] =
                        (__bf16)vv;
                }
            }
}

// Split-K (4 slices of 512) GEMM for w2: C(+)= A[8192][2048-slice] @ W2^T.
// 128x128 tile per slice, per-wave 64x64 (32 FLOP/LDS-byte, 2x the 64-tile
// kernel), grid (4,64,4)=1024 blocks -> 4/CU. Epilogue: atomicAdd fp32 into
// x, which already holds the residual from the wo-GEMM.
__global__ __launch_bounds__(256) void gemm_w2_splitk(
    const __bf16* __restrict__ A, const __bf16* __restrict__ Bw,
    float* __restrict__ Cout) {
    __shared__ __align__(16) __bf16 lds[2][2][128 * 32];
    const int tid = threadIdx.x;
    const int w = tid >> 6, lane = tid & 63;
    const int l15 = lane & 15, g4 = lane >> 4;
    const int wr = w >> 1, wc = w & 1;
    const int bm = blockIdx.y * 128, bn = blockIdx.x * 128;
    const int kz = blockIdx.z * 512;          // K-slice base (stride HIDN)
    const int lrow = lane >> 2, lc8 = (lane & 3) * 8;
    const int chunk0 = w * 2;

    f32x4 acc[4][4];
    #pragma unroll
    for (int m = 0; m < 4; m++)
        #pragma unroll
        for (int n = 0; n < 4; n++) acc[m][n] = (f32x4){0.f, 0.f, 0.f, 0.f};

    auto stage = [&](int buf, int k0) {
        #pragma unroll
        for (int c = 0; c < 2; c++) {
            int chunk = chunk0 + c;
            const __bf16* ga = A + (size_t)(bm + chunk * 16 + lrow) * HIDN + kz + k0 + lc8;
            gload16(ga, &lds[buf][0][chunk * 512]);
            const __bf16* gb = Bw + (size_t)(bn + chunk * 16 + lrow) * HIDN + kz + k0 + lc8;
            gload16(gb, &lds[buf][1][chunk * 512]);
        }
    };

    stage(0, 0);
    __syncthreads();
    const int NT = 512 >> 5;   // 16
    int cur = 0;
    for (int t = 0; t < NT; t++) {
        if (t + 1 < NT) stage(cur ^ 1, (t + 1) << 5);
        const __bf16* Al = &lds[cur][0][0];
        const __bf16* Bl = &lds[cur][1][0];
        bf16x8 af[4], bfr[4];
        #pragma unroll
        for (int m = 0; m < 4; m++)
            af[m] = *(const bf16x8*)&Al[(wr * 64 + m * 16 + l15) * 32 + g4 * 8];
        #pragma unroll
        for (int n = 0; n < 4; n++)
            bfr[n] = *(const bf16x8*)&Bl[(wc * 64 + n * 16 + l15) * 32 + g4 * 8];
        #pragma unroll
        for (int m = 0; m < 4; m++)
            #pragma unroll
            for (int n = 0; n < 4; n++)
                acc[m][n] = __builtin_amdgcn_mfma_f32_16x16x32_bf16(af[m], bfr[n], acc[m][n], 0, 0, 0);
        __syncthreads();
        cur ^= 1;
    }

    #pragma unroll
    for (int m = 0; m < 4; m++)
        #pragma unroll
        for (int n = 0; n < 4; n++)
            #pragma unroll
            for (int r = 0; r < 4; r++) {
                size_t row = bm + wr * 64 + m * 16 + g4 * 4 + r;
                int col = bn + wc * 64 + n * 16 + l15;
                atomicAdd(&Cout[row * Dd + col], acc[m][n][r]);
            }
}

// 64x64 tile variant for the N=512, K=512 wo GEMM: 1024 blocks -> 4/CU.
__global__ __launch_bounds__(256) void gemm_bt_mfma64(
    const __bf16* __restrict__ A, const __bf16* __restrict__ Bw,
    const float* __restrict__ res, float* __restrict__ Cout,
    int N, int K) {
    __shared__ __align__(16) __bf16 lds[2][2][64 * 32];
    const int tid = threadIdx.x;
    const int w = tid >> 6, lane = tid & 63;
    const int l15 = lane & 15, g4 = lane >> 4;
    const int wr = w >> 1, wc = w & 1;
    const int bm = blockIdx.y * 64, bn = blockIdx.x * 64;
    const int srow = tid >> 2, scol8 = (tid & 3) * 8;

    f32x4 acc[2][2];
    #pragma unroll
    for (int m = 0; m < 2; m++)
        #pragma unroll
        for (int n = 0; n < 2; n++) acc[m][n] = (f32x4){0.f, 0.f, 0.f, 0.f};

    auto stage = [&](int buf, int k0) {
        gload16(A + (size_t)(bm + srow) * K + k0 + scol8, &lds[buf][0][srow * 32 + scol8]);
        gload16(Bw + (size_t)(bn + srow) * K + k0 + scol8, &lds[buf][1][srow * 32 + scol8]);
    };

    stage(0, 0);
    __syncthreads();
    const int NT = K >> 5;
    int cur = 0;
    for (int t = 0; t < NT; t++) {
        if (t + 1 < NT) stage(cur ^ 1, (t + 1) << 5);
        const __bf16* Al = &lds[cur][0][0];
        const __bf16* Bl = &lds[cur][1][0];
        bf16x8 af[2], bfr[2];
        #pragma unroll
        for (int m = 0; m < 2; m++)
            af[m] = *(const bf16x8*)&Al[(wr * 32 + m * 16 + l15) * 32 + g4 * 8];
        #pragma unroll
        for (int n = 0; n < 2; n++)
            bfr[n] = *(const bf16x8*)&Bl[(wc * 32 + n * 16 + l15) * 32 + g4 * 8];
        #pragma unroll
        for (int m = 0; m < 2; m++)
            #pragma unroll
            for (int n = 0; n < 2; n++)
                acc[m][n] = __builtin_amdgcn_mfma_f32_16x16x32_bf16(af[m], bfr[n], acc[m][n], 0, 0, 0);
        __syncthreads();
        cur ^= 1;
    }

    #pragma unroll
    for (int m = 0; m < 2; m++)
        #pragma unroll
        for (int n = 0; n < 2; n++)
            #pragma unroll
            for (int r = 0; r < 4; r++) {
                size_t row = bm + wr * 32 + m * 16 + g4 * 4 + r;
                int col = bn + wc * 32 + n * 16 + l15;
                Cout[row * N + col] = acc[m][n][r] + res[row * N + col];
            }
}

// G = silu(A@W1^T) * (A@W3^T), bf16 out.
__global__ __launch_bounds__(256) void gemm_swiglu_mfma(
    const __bf16* __restrict__ A, const __bf16* __restrict__ W1,
    const __bf16* __restrict__ W3, __bf16* __restrict__ G,
    int N, int K) {
    __shared__ __align__(16) __bf16 lds[2][3][128 * 32];
    const int tid = threadIdx.x;
    const int w = tid >> 6, lane = tid & 63;
    const int l15 = lane & 15, g4 = lane >> 4;
    const int wr = w >> 1, wc = w & 1;
    const int bm = blockIdx.y * 128, bn = blockIdx.x * 128;
    const int lrow = lane >> 2, lc8 = (lane & 3) * 8;
    const int chunk0 = w * 2;

    f32x4 acc1[4][4], acc3[4][4];
    #pragma unroll
    for (int m = 0; m < 4; m++)
        #pragma unroll
        for (int n = 0; n < 4; n++) {
            acc1[m][n] = (f32x4){0.f, 0.f, 0.f, 0.f};
            acc3[m][n] = (f32x4){0.f, 0.f, 0.f, 0.f};
        }

    auto stage = [&](int buf, int k0) {
        #pragma unroll
        for (int c = 0; c < 2; c++) {
            int chunk = chunk0 + c;
            const __bf16* ga = A + (size_t)(bm + chunk * 16 + lrow) * K + k0 + lc8;
            gload16(ga, &lds[buf][0][chunk * 512]);
            const __bf16* g1 = W1 + (size_t)(bn + chunk * 16 + lrow) * K + k0 + lc8;
            gload16(g1, &lds[buf][1][chunk * 512]);
            const __bf16* g3 = W3 + (size_t)(bn + chunk * 16 + lrow) * K + k0 + lc8;
            gload16(g3, &lds[buf][2][chunk * 512]);
        }
    };

    stage(0, 0);
    __syncthreads();
    const int NT = K >> 5;
    int cur = 0;
    for (int t = 0; t < NT; t++) {
        if (t + 1 < NT) stage(cur ^ 1, (t + 1) << 5);
        const __bf16* Al = &lds[cur][0][0];
        const __bf16* B1 = &lds[cur][1][0];
        const __bf16* B3 = &lds[cur][2][0];
        bf16x8 af[4];
        #pragma unroll
        for (int m = 0; m < 4; m++)
            af[m] = *(const bf16x8*)&Al[(wr * 64 + m * 16 + l15) * 32 + g4 * 8];
        #pragma unroll
        for (int n = 0; n < 4; n++) {
            bf16x8 b1 = *(const bf16x8*)&B1[(wc * 64 + n * 16 + l15) * 32 + g4 * 8];
            bf16x8 b3 = *(const bf16x8*)&B3[(wc * 64 + n * 16 + l15) * 32 + g4 * 8];
            #pragma unroll
            for (int m = 0; m < 4; m++) {
                acc1[m][n] = __builtin_amdgcn_mfma_f32_16x16x32_bf16(af[m], b1, acc1[m][n], 0, 0, 0);
                acc3[m][n] = __builtin_amdgcn_mfma_f32_16x16x32_bf16(af[m], b3, acc3[m][n], 0, 0, 0);
            }
        }
        __syncthreads();
        cur ^= 1;
    }

    #pragma unroll
    for (int m = 0; m < 4; m++)
        #pragma unroll
        for (int n = 0; n < 4; n++)
            #pragma unroll
            for (int r = 0; r < 4; r++) {
                size_t row = bm + wr * 64 + m * 16 + g4 * 4 + r;
                size_t col = bn + wc * 64 + n * 16 + l15;
                float a1 = acc1[m][n][r];
                float sig = 1.0f / (1.0f + __expf(-a1));
                G[row * N + col] = (__bf16)(a1 * sig * acc3[m][n][r]);
            }
}

// Flash attention (8-wave blocks + LDS double buffer): sigma-permuted swapped
// QK^T keeps P in registers; KVBLK=64 K/V stage shared by 8 waves; one
// __syncthreads per tile. T14 reg prefetch; T5 setprio; T13 defer-max;
// rotated-V panels; XCD remap.
__global__ __launch_bounds__(512) void attn_mfma_kernel(
    const __bf16* __restrict__ q, const __bf16* __restrict__ k,
    const __bf16* __restrict__ v, __bf16* __restrict__ o) {
    __shared__ __align__(16) __bf16 Ks[2][64][72];
    __shared__ __align__(16) unsigned int VtW[2][64 * 36];   // [buf][d][pair-word rotated]

    int tid = threadIdx.x;            // 0..511
    int w = tid >> 6;                 // wave 0..7
    int lane = tid & 63;
    int l15 = lane & 15;
    int g = lane >> 4;
    // XCD remap: the 16 q-tile blocks of one (b,h) land on XCD i%8.
    int i = blockIdx.x;               // 0..511
    int xcd = i & 7, jj = i >> 3;     // jj 0..63
    int bh = xcd * 4 + (jj >> 4);
    int qtile = jj & 15;
    int b = bh >> 3, h = bh & 7;
    int qbase = qtile * 128;

    const __bf16* qp = q + (size_t)b * Tt * Dd + (size_t)h * DHd;
    const __bf16* kp = k + (size_t)b * Tt * Dd + (size_t)h * DHd;
    const __bf16* vp = v + (size_t)b * Tt * Dd + (size_t)h * DHd;

    // staging coordinates (512 threads share one 64-row K/V tile)
    int krow = tid >> 3;              // 0..63
    int ksc8 = (tid & 7) * 8;
    int r2v  = tid >> 4;              // V pair index 0..31
    int sc4  = (tid & 15) * 4;        // V d-col base
    int sgrow = 8 * (l15 >> 2) + (l15 & 3);   // sigma base row

    bf16x8 qa[2];
    {
        const __bf16* qrow = qp + (size_t)(qbase + w * 16 + l15) * Dd;
        qa[0] = *(const bf16x8*)(qrow + g * 8);
        qa[1] = *(const bf16x8*)(qrow + 32 + g * 8);
    }

    f32x4 oacc[4];
    #pragma unroll
    for (int i2 = 0; i2 < 4; i2++) oacc[i2] = (f32x4){0.f, 0.f, 0.f, 0.f};
    float mrun = -1e30f;
    float lrun = 0.f;

    bf16x8 kreg;
    bf16x4 vreg0, vreg1;
    auto ldkv = [&](int t) {
        size_t base = (size_t)(t * 64) * Dd;
        kreg  = *(const bf16x8*)(kp + base + (size_t)krow * Dd + ksc8);
        vreg0 = *(const bf16x4*)(vp + base + (size_t)(2 * r2v) * Dd + sc4);
        vreg1 = *(const bf16x4*)(vp + base + (size_t)(2 * r2v + 1) * Dd + sc4);
    };
    auto stash = [&](int buf) {
        *(bf16x8*)&Ks[buf][krow][ksc8] = kreg;
        const unsigned short* v0 = (const unsigned short*)&vreg0;
        const unsigned short* v1 = (const unsigned short*)&vreg1;
        #pragma unroll
        for (int j = 0; j < 4; j++) {
            int d = sc4 + j;
            int col = (r2v + 4 * ((d >> 3) & 7)) & 31;
            unsigned int word = (unsigned int)v0[j] | ((unsigned int)v1[j] << 16);
            VtW[buf][d * 36 + col] = word;
        }
    };

    const int NT = Tt / 64;
    ldkv(0);
    stash(0);
    ldkv(1);
    __syncthreads();   // buf0 ready

    for (int t = 0; t < NT; t++) {
        int cur = t & 1;
        // QK^T swapped from buf[cur]
        f32x4 s4[4];
        __builtin_amdgcn_s_setprio(1);
        #pragma unroll
        for (int c = 0; c < 4; c++) {
            int row = sgrow + (c & 1) * 32 + (c >> 1) * 4;
            s4[c] = (f32x4){0.f, 0.f, 0.f, 0.f};
            bf16x8 kb0 = *(const bf16x8*)&Ks[cur][row][g * 8];
            s4[c] = __builtin_amdgcn_mfma_f32_16x16x32_bf16(kb0, qa[0], s4[c], 0, 0, 0);
            bf16x8 kb1 = *(const bf16x8*)&Ks[cur][row][32 + g * 8];
            s4[c] = __builtin_amdgcn_mfma_f32_16x16x32_bf16(kb1, qa[1], s4[c], 0, 0, 0);
        }
        __builtin_amdgcn_s_setprio(0);

        // write next tile's regs into buf[cur^1]; issue t+2 global loads
        if (t + 1 < NT) stash(cur ^ 1);
        if (t + 2 < NT) ldkv(t + 2);

        // per-lane max over 16 scores (one q-row slice); defer-max (T13)
        float lm = fmaxf(fmaxf(fmaxf(s4[0][0], s4[0][1]), fmaxf(s4[0][2], s4[0][3])),
                         fmaxf(fmaxf(s4[1][0], s4[1][1]), fmaxf(s4[1][2], s4[1][3])));
        lm = fmaxf(lm, fmaxf(fmaxf(s4[2][0], s4[2][1]), fmaxf(s4[2][2], s4[2][3])));
        lm = fmaxf(lm, fmaxf(fmaxf(s4[3][0], s4[3][1]), fmaxf(s4[3][2], s4[3][3])));
        bool near = (lm - mrun <= 8.f);
        if (!__all((int)near)) {
            float tm = fmaxf(lm, __shfl_xor(lm, 16));
            tm = fmaxf(tm, __shfl_xor(tm, 32));
            float mnew = fmaxf(mrun, tm);
            float alpha = exp2f(mrun - mnew);
            mrun = mnew;
            lrun *= alpha;
            float ar[4];
            #pragma unroll
            for (int r = 0; r < 4; r++) ar[r] = __shfl(alpha, 20 * g + r);
            #pragma unroll
            for (int d2 = 0; d2 < 4; d2++)
                #pragma unroll
                for (int r = 0; r < 4; r++) oacc[d2][r] *= ar[r];
        }
        // P = exp2(s - m); lane-partial l; PV A-frags built in-lane
        float psum = 0.f;
        bf16x8 pa0, pa1;
        #pragma unroll
        for (int cc = 0; cc < 2; cc++)
            #pragma unroll
            for (int r = 0; r < 4; r++) {
                float e0 = exp2f(s4[2 * cc][r] - mrun);
                float e1 = exp2f(s4[2 * cc + 1][r] - mrun);
                psum += e0 + e1;
                pa0[cc * 4 + r] = (__bf16)e0;
                pa1[cc * 4 + r] = (__bf16)e1;
            }
        lrun += psum;

        __builtin_amdgcn_s_setprio(1);
        #pragma unroll
        for (int d2 = 0; d2 < 4; d2++) {
            int d = d2 * 16 + l15;
            int rot = ((2 * d2 + (l15 >> 3)) & 7) * 4;
            const unsigned int* vrow = VtW[cur] + d * 36;
            bf16x8 vb0 = *(const bf16x8*)(vrow + ((4 * g + rot) & 31));
            bf16x8 vb1 = *(const bf16x8*)(vrow + ((16 + 4 * g + rot) & 31));
            oacc[d2] = __builtin_amdgcn_mfma_f32_16x16x32_bf16(pa0, vb0, oacc[d2], 0, 0, 0);
            oacc[d2] = __builtin_amdgcn_mfma_f32_16x16x32_bf16(pa1, vb1, oacc[d2], 0, 0, 0);
        }
        __builtin_amdgcn_s_setprio(0);

        __syncthreads();   // single barrier per tile (dbuf invariant)
    }

    // total l per q-row (reduce the 4 g-slices), then fetch per-output-row
    lrun += __shfl_xor(lrun, 16);
    lrun += __shfl_xor(lrun, 32);
    float lr[4];
    #pragma unroll
    for (int r = 0; r < 4; r++) lr[r] = __shfl(lrun, 20 * g + r);

    __bf16* op = o + (size_t)b * Tt * Dd + (size_t)h * DHd;
    #pragma unroll
    for (int d2 = 0; d2 < 4; d2++)
        #pragma unroll
        for (int r = 0; r < 4; r++)
            op[(size_t)(qbase + w * 16 + g * 4 + r) * Dd + d2 * 16 + l15] =
                (__bf16)(oacc[d2][r] / lr[r]);
}

// segment scan + fused count atomics (run-length aggregated)
__global__ void seg_scan_kernel(const int* __restrict__ tokens, int* __restrict__ segid,
                                float* __restrict__ cnt) {
    int b = blockIdx.x;
    int tid = threadIdx.x;
    const int* trow = tokens + (size_t)b * Tt;
    int base = tid * 8;
    int inc[8];
    int run = 0;
    #pragma unroll
    for (int i = 0; i < 8; i++) {
        int tk = trow[base + i];
        tk = tk < 0 ? 0 : (tk > 255 ? 255 : tk);
        run += is_sep(tk);
        inc[i] = run;
    }
    __shared__ int part[256];
    part[tid] = run;
    __syncthreads();
    for (int off = 1; off < 256; off <<= 1) {
        int vv = (tid >= off) ? part[tid - off] : 0;
        __syncthreads();
        part[tid] += vv;
        __syncthreads();
    }
    int exc = part[tid] - run;
    int sid[8];
    #pragma unroll
    for (int i = 0; i < 8; i++) {
        sid[i] = exc + inc[i] + b * (Tt + 1);
        segid[(size_t)b * Tt + base + i] = sid[i];
    }
    int curid = sid[0];
    float c = 1.0f;
    #pragma unroll
    for (int i = 1; i < 8; i++) {
        if (sid[i] == curid) c += 1.0f;
        else { atomicAdd(&cnt[curid], c); curid = sid[i]; c = 1.0f; }
    }
    atomicAdd(&cnt[curid], c);
}

__global__ void seg_accum_kernel(const float* __restrict__ h, const int* __restrict__ segid,
                                 float* __restrict__ segsum) {
    size_t idx = (size_t)blockIdx.x * blockDim.x + threadIdx.x;
    if (idx >= BTD) return;
    size_t row = idx >> 9;
    int d = idx & 511;
    atomicAdd(&segsum[(size_t)segid[row] * Dd + d], h[idx]);
}

__global__ void seg_final_kernel(const float* __restrict__ h, const float* __restrict__ segsum,
                                 const float* __restrict__ cnt, const int* __restrict__ segid,
                                 float* __restrict__ out) {
    size_t idx = (size_t)blockIdx.x * blockDim.x + threadIdx.x;
    if (idx >= BTD) return;
    size_t row = idx >> 9;
    int d = idx & 511;
    int s = segid[row];
    float mean = segsum[(size_t)s * Dd + d] / fmaxf(cnt[s], 1.0f);
    out[idx] = 0.5f * h[idx] + 0.5f * mean;
}

extern "C" void kernel_launch(void* const* d_in, const int* in_sizes, int n_in,
                              void* d_out, int out_size, void* d_ws, size_t ws_size,
                              hipStream_t stream) {
    const int*   tokens       = (const int*)d_in[0];
    const float* embedw       = (const float*)d_in[1];
    const float* attn_norm_w  = (const float*)d_in[2];
    const float* wq           = (const float*)d_in[3];
    const float* wk           = (const float*)d_in[4];
    const float* wv           = (const float*)d_in[5];
    const float* wo           = (const float*)d_in[6];
    const float* ffn_norm_w   = (const float*)d_in[7];
    const float* w1           = (const float*)d_in[8];
    const float* w2           = (const float*)d_in[9];
    const float* w3           = (const float*)d_in[10];
    const float* final_norm_w = (const float*)d_in[11];
    float* out = (float*)d_out;
    float* ws  = (float*)d_ws;

    float*  x    = ws;
    __bf16* qkvo = (__bf16*)(ws + BTD);
    __bf16* qb   = qkvo;
    __bf16* kb   = qkvo + BTD;
    __bf16* vb   = qkvo + 2 * BTD;
    __bf16* obuf = qkvo + 3 * BTD;
    __bf16* gbuf = qkvo;                    // overlay (FFN phase)
    float*  segsum = ws + BTD;              // overlay (qkvo dead after last w2)
    __bf16* xnb  = (__bf16*)(ws + 3 * BTD);
    __bf16* wb   = (__bf16*)(ws + 3 * BTD + BTD / 2);
    float*  cosb = ws + 3 * BTD + BTD / 2 + 8388608;
    float*  sinb = cosb + (size_t)Tt * 32;
    float*  segcnt = sinb + (size_t)Tt * 32;
    int*    segid  = (int*)(segcnt + Bq * (Tt + 1));

    __bf16* wqkvb = wb;                     // [L][1536][512]
    __bf16* wob = wb + 3145728;             // wo|w1|w3|w2 contiguous from here
    __bf16* w1b = wb + 4194304;
    __bf16* w3b = wb + 8388608;
    __bf16* w2b = wb + 12582912;

    cvt_qkv_kernel<<<1536, 256, 0, stream>>>(wq, wk, wv, wqkvb);
    cvt_w_kernel<<<6656, 256, 0, stream>>>(wo, w1, w3, w2, wob);

    embed_kernel<<<(int)((BTD / 4 + 255) / 256), 256, 0, stream>>>(tokens, embedw, x);
    rope_table_kernel<<<(Tt * 32 + 255) / 256, 256, 0, stream>>>(cosb, sinb);

    dim3 gqkv(12, 64);    // N=1536, 128x128 tiles
    dim3 g64(8, 128);     // N=512, 64x64 tiles (wo)
    dim3 gs(16, 64);      // N=2048, 128x128 tiles
    dim3 gw2(4, 64, 4);   // w2 split-K: 128x128 tiles x 4 K-slices
    dim3 ga(512);         // attn: 512 blocks x 512 threads, XCD remap in-kernel
    int grms = BT / 4;    // wave-per-row rmsnorm

    for (int l = 0; l < Ll; l++) {
        size_t oDD = (size_t)l * Dd * Dd;
        size_t oHD = (size_t)l * HIDN * Dd;
        rmsnorm_bf16_kernel<<<grms, 256, 0, stream>>>(x, attn_norm_w + (size_t)l * Dd, xnb);
        gemm_bt_mfma<2><<<gqkv, 256, 0, stream>>>(xnb, wqkvb + (size_t)l * 786432, nullptr, qb,
                                                  1536, Dd, cosb, sinb);
        attn_mfma_kernel<<<ga, 512, 0, stream>>>(qb, kb, vb, obuf);
        gemm_bt_mfma64<<<g64, 256, 0, stream>>>(obuf, wob + oDD, x, x, Dd, Dd);
        rmsnorm_bf16_kernel<<<grms, 256, 0, stream>>>(x, ffn_norm_w + (size_t)l * Dd, xnb);
        gemm_swiglu_mfma<<<gs, 256, 0, stream>>>(xnb, w1b + oHD, w3b + oHD, gbuf, HIDN, Dd);
        gemm_w2_splitk<<<gw2, 256, 0, stream>>>(gbuf, w2b + oHD, x);
    }

    // tail: in-place final norm, then segment pooling
    rmsnorm_inplace_kernel<<<grms, 256, 0, stream>>>(x, final_norm_w);
    hipMemsetAsync(segsum, 0, (size_t)Bq * (Tt + 1) * Dd * sizeof(float), stream);
    hipMemsetAsync(segcnt, 0, (size_t)Bq * (Tt + 1) * sizeof(float), stream);
    seg_scan_kernel<<<Bq, 256, 0, stream>>>(tokens, segid, segcnt);
    seg_accum_kernel<<<(int)((BTD + 255) / 256), 256, 0, stream>>>(x, segid, segsum);
    seg_final_kernel<<<(int)((BTD + 255) / 256), 256, 0, stream>>>(x, segsum, segcnt, segid, out);
}

// Round 24
// 971.371 us; speedup vs baseline: 1.0996x; 1.0996x over previous
//
#include <hip/hip_runtime.h>
#include <math.h>

#define Bq 4
#define Tt 2048
#define Dd 512
#define Hh 8
#define Ll 4
#define HIDN 2048
#define DHd 64
#define BT (Bq*Tt)                 // 8192
#define BTD ((size_t)BT*Dd)        // 4194304

typedef __attribute__((ext_vector_type(8))) __bf16 bf16x8;
typedef __attribute__((ext_vector_type(4))) __bf16 bf16x4;
typedef __attribute__((ext_vector_type(2))) __bf16 bf16x2;
typedef __attribute__((ext_vector_type(4))) float f32x4;

static __device__ __forceinline__ int is_sep(int t) {
    const unsigned long long w0 = 0xFC00FFFF00002600ULL;
    const unsigned long long w1 = 0x7800000078000001ULL;
    if (t < 64)  return (int)((w0 >> t) & 1ULL);
    if (t < 128) return (int)((w1 >> (t - 64)) & 1ULL);
    return 0;
}

static __device__ __forceinline__ void gload16(const void* g, void* l) {
    __builtin_amdgcn_global_load_lds(
        (const __attribute__((address_space(1))) void*)g,
        (__attribute__((address_space(3))) void*)l, 16, 0, 0);
}

__global__ void embed_kernel(const int* __restrict__ tokens, const float* __restrict__ embed,
                             float* __restrict__ x) {
    size_t idx = (size_t)blockIdx.x * blockDim.x + threadIdx.x;
    if (idx >= BTD / 4) return;
    size_t row = idx >> 7;
    int tk = tokens[row];
    tk = tk < 0 ? 0 : (tk > 255 ? 255 : tk);
    const float4* src = (const float4*)(embed + (size_t)tk * Dd);
    ((float4*)x)[idx] = src[idx & 127];
}

__global__ void rope_table_kernel(float* __restrict__ cosb, float* __restrict__ sinb) {
    int idx = blockIdx.x * blockDim.x + threadIdx.x;
    if (idx >= Tt * 32) return;
    int t = idx >> 5, j = idx & 31;
    float inv = powf(10000.0f, -(2.0f * j) / 64.0f);
    float ang = (float)t * inv;
    cosb[idx] = cosf(ang);
    sinb[idx] = sinf(ang);
}

// fused fp32->bf16 conversion for wo|w1|w3|w2 (contiguous dest arena)
__global__ void cvt_w_kernel(const float* __restrict__ wo, const float* __restrict__ w1,
                             const float* __restrict__ w3, const float* __restrict__ w2,
                             __bf16* __restrict__ dst) {
    int i = blockIdx.x * blockDim.x + threadIdx.x;   // 1703936 groups of 8
    if (i >= 1703936) return;
    const float* src;
    if (i < 131072)       src = wo + (size_t)i * 8;
    else if (i < 655360)  src = w1 + (size_t)(i - 131072) * 8;
    else if (i < 1179648) src = w3 + (size_t)(i - 655360) * 8;
    else                  src = w2 + (size_t)(i - 1179648) * 8;
    float4 a = *(const float4*)src;
    float4 b = *(const float4*)(src + 4);
    bf16x8 o8;
    o8[0] = (__bf16)a.x; o8[1] = (__bf16)a.y; o8[2] = (__bf16)a.z; o8[3] = (__bf16)a.w;
    o8[4] = (__bf16)b.x; o8[5] = (__bf16)b.y; o8[6] = (__bf16)b.z; o8[7] = (__bf16)b.w;
    *(bf16x8*)(dst + (size_t)i * 8) = o8;
}

// concat wq/wk/wv -> wqkv[L][1536][512] bf16
__global__ void cvt_qkv_kernel(const float* __restrict__ wq, const float* __restrict__ wk,
                               const float* __restrict__ wv, __bf16* __restrict__ out) {
    int i = blockIdx.x * blockDim.x + threadIdx.x;   // 393216
    if (i >= 393216) return;
    int l = i / 98304;
    int r = i - l * 98304;
    int t = r >> 15;             // /32768
    int pos8 = r & 32767;
    const float* src = (t == 0 ? wq : (t == 1 ? wk : wv)) + (size_t)l * 262144 + (size_t)pos8 * 8;
    float4 a = *(const float4*)src;
    float4 b = *(const float4*)(src + 4);
    bf16x8 o8;
    o8[0] = (__bf16)a.x; o8[1] = (__bf16)a.y; o8[2] = (__bf16)a.z; o8[3] = (__bf16)a.w;
    o8[4] = (__bf16)b.x; o8[5] = (__bf16)b.y; o8[6] = (__bf16)b.z; o8[7] = (__bf16)b.w;
    *(bf16x8*)(out + (size_t)i * 8) = o8;
}

// fp32 in, bf16 out (layer norms)
__global__ void rmsnorm_bf16_kernel(const float* __restrict__ x, const float* __restrict__ w,
                                    __bf16* __restrict__ y) {
    int row = blockIdx.x * 4 + (threadIdx.x >> 6);
    int lane = threadIdx.x & 63;
    const float* xr = x + (size_t)row * Dd + lane * 8;
    float4 a = *(const float4*)xr;
    float4 b = *(const float4*)(xr + 4);
    float ss = a.x * a.x + a.y * a.y + a.z * a.z + a.w * a.w
             + b.x * b.x + b.y * b.y + b.z * b.z + b.w * b.w;
    #pragma unroll
    for (int off = 1; off < 64; off <<= 1) ss += __shfl_xor(ss, off);
    float scale = rsqrtf(ss * (1.0f / Dd) + 1e-6f);
    const float* wr = w + lane * 8;
    float4 wa = *(const float4*)wr;
    float4 wb = *(const float4*)(wr + 4);
    bf16x8 o;
    o[0] = (__bf16)(a.x * scale * wa.x); o[1] = (__bf16)(a.y * scale * wa.y);
    o[2] = (__bf16)(a.z * scale * wa.z); o[3] = (__bf16)(a.w * scale * wa.w);
    o[4] = (__bf16)(b.x * scale * wb.x); o[5] = (__bf16)(b.y * scale * wb.y);
    o[6] = (__bf16)(b.z * scale * wb.z); o[7] = (__bf16)(b.w * scale * wb.w);
    *(bf16x8*)(y + (size_t)row * Dd + lane * 8) = o;
}

// Final RMSNorm, in-place on x.
__global__ void rmsnorm_inplace_kernel(float* __restrict__ x, const float* __restrict__ w) {
    int row = blockIdx.x * 4 + (threadIdx.x >> 6);
    int lane = threadIdx.x & 63;
    float* xr = x + (size_t)row * Dd + lane * 8;
    float4 a = *(const float4*)xr;
    float4 b = *(const float4*)(xr + 4);
    float ss = a.x * a.x + a.y * a.y + a.z * a.z + a.w * a.w
             + b.x * b.x + b.y * b.y + b.z * b.z + b.w * b.w;
    #pragma unroll
    for (int off = 1; off < 64; off <<= 1) ss += __shfl_xor(ss, off);
    float scale = rsqrtf(ss * (1.0f / Dd) + 1e-6f);
    const float* wr = w + lane * 8;
    float4 wa = *(const float4*)wr;
    float4 wb = *(const float4*)(wr + 4);
    *(float4*)xr = make_float4(a.x * scale * wa.x, a.y * scale * wa.y,
                               a.z * scale * wa.z, a.w * scale * wa.w);
    *(float4*)(xr + 4) = make_float4(b.x * scale * wb.x, b.y * scale * wb.y,
                                     b.z * scale * wb.z, b.w * scale * wb.w);
}

// C = A(bf16) @ Bw(bf16)^T. 128x128 tile, BK=32, double-buffered gload_lds.
// EPI 0: bf16 out stride N. EPI 1: f32 out + f32 residual.
// EPI 2: bf16 QKV split + fused RoPE on q/k cols (q also scaled 0.125*log2e).
template<int EPI>
__global__ __launch_bounds__(256) void gemm_bt_mfma(
    const __bf16* __restrict__ A, const __bf16* __restrict__ Bw,
    const float* __restrict__ res, void* __restrict__ Cout,
    int N, int K,
    const float* __restrict__ cosb, const float* __restrict__ sinb) {
    __shared__ __align__(16) __bf16 lds[2][2][128 * 32];
    const int tid = threadIdx.x;
    const int w = tid >> 6, lane = tid & 63;
    const int l15 = lane & 15, g4 = lane >> 4;
    const int wr = w >> 1, wc = w & 1;
    const int bm = blockIdx.y * 128, bn = blockIdx.x * 128;
    const int lrow = lane >> 2, lc8 = (lane & 3) * 8;
    const int chunk0 = w * 2;

    f32x4 acc[4][4];
    #pragma unroll
    for (int m = 0; m < 4; m++)
        #pragma unroll
        for (int n = 0; n < 4; n++) acc[m][n] = (f32x4){0.f, 0.f, 0.f, 0.f};

    auto stage = [&](int buf, int k0) {
        #pragma unroll
        for (int c = 0; c < 2; c++) {
            int chunk = chunk0 + c;
            const __bf16* ga = A + (size_t)(bm + chunk * 16 + lrow) * K + k0 + lc8;
            gload16(ga, &lds[buf][0][chunk * 512]);
            const __bf16* gb = Bw + (size_t)(bn + chunk * 16 + lrow) * K + k0 + lc8;
            gload16(gb, &lds[buf][1][chunk * 512]);
        }
    };

    stage(0, 0);
    __syncthreads();
    const int NT = K >> 5;
    int cur = 0;
    for (int t = 0; t < NT; t++) {
        if (t + 1 < NT) stage(cur ^ 1, (t + 1) << 5);
        const __bf16* Al = &lds[cur][0][0];
        const __bf16* Bl = &lds[cur][1][0];
        bf16x8 af[4], bfr[4];
        #pragma unroll
        for (int m = 0; m < 4; m++)
            af[m] = *(const bf16x8*)&Al[(wr * 64 + m * 16 + l15) * 32 + g4 * 8];
        #pragma unroll
        for (int n = 0; n < 4; n++)
            bfr[n] = *(const bf16x8*)&Bl[(wc * 64 + n * 16 + l15) * 32 + g4 * 8];
        #pragma unroll
        for (int m = 0; m < 4; m++)
            #pragma unroll
            for (int n = 0; n < 4; n++)
                acc[m][n] = __builtin_amdgcn_mfma_f32_16x16x32_bf16(af[m], bfr[n], acc[m][n], 0, 0, 0);
        __syncthreads();
        cur ^= 1;
    }

    #pragma unroll
    for (int m = 0; m < 4; m++)
        #pragma unroll
        for (int n = 0; n < 4; n++)
            #pragma unroll
            for (int r = 0; r < 4; r++) {
                size_t row = bm + wr * 64 + m * 16 + g4 * 4 + r;
                int col = bn + wc * 64 + n * 16 + l15;
                if (EPI == 0) {
                    ((__bf16*)Cout)[row * N + col] = (__bf16)acc[m][n][r];
                } else if (EPI == 1) {
                    ((float*)Cout)[row * N + col] = acc[m][n][r] + res[row * N + col];
                } else {
                    float vv = acc[m][n][r];
                    float vp = __shfl_xor(vv, 1);   // rope pair partner (col^1)
                    if (col < 1024) {               // q or k: apply RoPE (uniform per n)
                        int trow = (int)(row & (Tt - 1));
                        int p = (col & 63) >> 1;
                        float c = cosb[trow * 32 + p];
                        float s = sinb[trow * 32 + p];
                        float x1 = (col & 1) ? vp : vv;
                        float x2 = (col & 1) ? vv : vp;
                        float rot = (col & 1) ? (x1 * s + x2 * c) : (x1 * c - x2 * s);
                        if (col < 512) rot *= 0.18033688011112043f;   // 0.125*log2(e)
                        vv = rot;
                    }
                    ((__bf16*)Cout)[(size_t)(col >> 9) * BTD + row * 512 + (col & 511)] =
                        (__bf16)vv;
                }
            }
}

// 64x64 tile variant for N=512 GEMMs (wo, w2): 1024 blocks -> 4 blocks/CU.
__global__ __launch_bounds__(256) void gemm_bt_mfma64(
    const __bf16* __restrict__ A, const __bf16* __restrict__ Bw,
    const float* __restrict__ res, float* __restrict__ Cout,
    int N, int K) {
    __shared__ __align__(16) __bf16 lds[2][2][64 * 32];
    const int tid = threadIdx.x;
    const int w = tid >> 6, lane = tid & 63;
    const int l15 = lane & 15, g4 = lane >> 4;
    const int wr = w >> 1, wc = w & 1;
    const int bm = blockIdx.y * 64, bn = blockIdx.x * 64;
    const int srow = tid >> 2, scol8 = (tid & 3) * 8;

    f32x4 acc[2][2];
    #pragma unroll
    for (int m = 0; m < 2; m++)
        #pragma unroll
        for (int n = 0; n < 2; n++) acc[m][n] = (f32x4){0.f, 0.f, 0.f, 0.f};

    auto stage = [&](int buf, int k0) {
        gload16(A + (size_t)(bm + srow) * K + k0 + scol8, &lds[buf][0][srow * 32 + scol8]);
        gload16(Bw + (size_t)(bn + srow) * K + k0 + scol8, &lds[buf][1][srow * 32 + scol8]);
    };

    stage(0, 0);
    __syncthreads();
    const int NT = K >> 5;
    int cur = 0;
    for (int t = 0; t < NT; t++) {
        if (t + 1 < NT) stage(cur ^ 1, (t + 1) << 5);
        const __bf16* Al = &lds[cur][0][0];
        const __bf16* Bl = &lds[cur][1][0];
        bf16x8 af[2], bfr[2];
        #pragma unroll
        for (int m = 0; m < 2; m++)
            af[m] = *(const bf16x8*)&Al[(wr * 32 + m * 16 + l15) * 32 + g4 * 8];
        #pragma unroll
        for (int n = 0; n < 2; n++)
            bfr[n] = *(const bf16x8*)&Bl[(wc * 32 + n * 16 + l15) * 32 + g4 * 8];
        #pragma unroll
        for (int m = 0; m < 2; m++)
            #pragma unroll
            for (int n = 0; n < 2; n++)
                acc[m][n] = __builtin_amdgcn_mfma_f32_16x16x32_bf16(af[m], bfr[n], acc[m][n], 0, 0, 0);
        __syncthreads();
        cur ^= 1;
    }

    #pragma unroll
    for (int m = 0; m < 2; m++)
        #pragma unroll
        for (int n = 0; n < 2; n++)
            #pragma unroll
            for (int r = 0; r < 4; r++) {
                size_t row = bm + wr * 32 + m * 16 + g4 * 4 + r;
                int col = bn + wc * 32 + n * 16 + l15;
                Cout[row * N + col] = acc[m][n][r] + res[row * N + col];
            }
}

// G = silu(A@W1^T) * (A@W3^T), bf16 out.
__global__ __launch_bounds__(256) void gemm_swiglu_mfma(
    const __bf16* __restrict__ A, const __bf16* __restrict__ W1,
    const __bf16* __restrict__ W3, __bf16* __restrict__ G,
    int N, int K) {
    __shared__ __align__(16) __bf16 lds[2][3][128 * 32];
    const int tid = threadIdx.x;
    const int w = tid >> 6, lane = tid & 63;
    const int l15 = lane & 15, g4 = lane >> 4;
    const int wr = w >> 1, wc = w & 1;
    const int bm = blockIdx.y * 128, bn = blockIdx.x * 128;
    const int lrow = lane >> 2, lc8 = (lane & 3) * 8;
    const int chunk0 = w * 2;

    f32x4 acc1[4][4], acc3[4][4];
    #pragma unroll
    for (int m = 0; m < 4; m++)
        #pragma unroll
        for (int n = 0; n < 4; n++) {
            acc1[m][n] = (f32x4){0.f, 0.f, 0.f, 0.f};
            acc3[m][n] = (f32x4){0.f, 0.f, 0.f, 0.f};
        }

    auto stage = [&](int buf, int k0) {
        #pragma unroll
        for (int c = 0; c < 2; c++) {
            int chunk = chunk0 + c;
            const __bf16* ga = A + (size_t)(bm + chunk * 16 + lrow) * K + k0 + lc8;
            gload16(ga, &lds[buf][0][chunk * 512]);
            const __bf16* g1 = W1 + (size_t)(bn + chunk * 16 + lrow) * K + k0 + lc8;
            gload16(g1, &lds[buf][1][chunk * 512]);
            const __bf16* g3 = W3 + (size_t)(bn + chunk * 16 + lrow) * K + k0 + lc8;
            gload16(g3, &lds[buf][2][chunk * 512]);
        }
    };

    stage(0, 0);
    __syncthreads();
    const int NT = K >> 5;
    int cur = 0;
    for (int t = 0; t < NT; t++) {
        if (t + 1 < NT) stage(cur ^ 1, (t + 1) << 5);
        const __bf16* Al = &lds[cur][0][0];
        const __bf16* B1 = &lds[cur][1][0];
        const __bf16* B3 = &lds[cur][2][0];
        bf16x8 af[4];
        #pragma unroll
        for (int m = 0; m < 4; m++)
            af[m] = *(const bf16x8*)&Al[(wr * 64 + m * 16 + l15) * 32 + g4 * 8];
        #pragma unroll
        for (int n = 0; n < 4; n++) {
            bf16x8 b1 = *(const bf16x8*)&B1[(wc * 64 + n * 16 + l15) * 32 + g4 * 8];
            bf16x8 b3 = *(const bf16x8*)&B3[(wc * 64 + n * 16 + l15) * 32 + g4 * 8];
            #pragma unroll
            for (int m = 0; m < 4; m++) {
                acc1[m][n] = __builtin_amdgcn_mfma_f32_16x16x32_bf16(af[m], b1, acc1[m][n], 0, 0, 0);
                acc3[m][n] = __builtin_amdgcn_mfma_f32_16x16x32_bf16(af[m], b3, acc3[m][n], 0, 0, 0);
            }
        }
        __syncthreads();
        cur ^= 1;
    }

    #pragma unroll
    for (int m = 0; m < 4; m++)
        #pragma unroll
        for (int n = 0; n < 4; n++)
            #pragma unroll
            for (int r = 0; r < 4; r++) {
                size_t row = bm + wr * 64 + m * 16 + g4 * 4 + r;
                size_t col = bn + wc * 64 + n * 16 + l15;
                float a1 = acc1[m][n][r];
                float sig = 1.0f / (1.0f + __expf(-a1));
                G[row * N + col] = (__bf16)(a1 * sig * acc3[m][n][r]);
            }
}

// Flash attention (8-wave blocks + LDS double buffer): sigma-permuted swapped
// QK^T keeps P in registers; KVBLK=64 K/V stage shared by 8 waves; one
// __syncthreads per tile. T14 reg prefetch; T5 setprio; T13 defer-max;
// rotated-V panels; XCD remap.
__global__ __launch_bounds__(512) void attn_mfma_kernel(
    const __bf16* __restrict__ q, const __bf16* __restrict__ k,
    const __bf16* __restrict__ v, __bf16* __restrict__ o) {
    __shared__ __align__(16) __bf16 Ks[2][64][72];
    __shared__ __align__(16) unsigned int VtW[2][64 * 36];   // [buf][d][pair-word rotated]

    int tid = threadIdx.x;            // 0..511
    int w = tid >> 6;                 // wave 0..7
    int lane = tid & 63;
    int l15 = lane & 15;
    int g = lane >> 4;
    // XCD remap: the 16 q-tile blocks of one (b,h) land on XCD i%8.
    int i = blockIdx.x;               // 0..511
    int xcd = i & 7, jj = i >> 3;     // jj 0..63
    int bh = xcd * 4 + (jj >> 4);
    int qtile = jj & 15;
    int b = bh >> 3, h = bh & 7;
    int qbase = qtile * 128;

    const __bf16* qp = q + (size_t)b * Tt * Dd + (size_t)h * DHd;
    const __bf16* kp = k + (size_t)b * Tt * Dd + (size_t)h * DHd;
    const __bf16* vp = v + (size_t)b * Tt * Dd + (size_t)h * DHd;

    // staging coordinates (512 threads share one 64-row K/V tile)
    int krow = tid >> 3;              // 0..63
    int ksc8 = (tid & 7) * 8;
    int r2v  = tid >> 4;              // V pair index 0..31
    int sc4  = (tid & 15) * 4;        // V d-col base
    int sgrow = 8 * (l15 >> 2) + (l15 & 3);   // sigma base row

    bf16x8 qa[2];
    {
        const __bf16* qrow = qp + (size_t)(qbase + w * 16 + l15) * Dd;
        qa[0] = *(const bf16x8*)(qrow + g * 8);
        qa[1] = *(const bf16x8*)(qrow + 32 + g * 8);
    }

    f32x4 oacc[4];
    #pragma unroll
    for (int i2 = 0; i2 < 4; i2++) oacc[i2] = (f32x4){0.f, 0.f, 0.f, 0.f};
    float mrun = -1e30f;
    float lrun = 0.f;

    bf16x8 kreg;
    bf16x4 vreg0, vreg1;
    auto ldkv = [&](int t) {
        size_t base = (size_t)(t * 64) * Dd;
        kreg  = *(const bf16x8*)(kp + base + (size_t)krow * Dd + ksc8);
        vreg0 = *(const bf16x4*)(vp + base + (size_t)(2 * r2v) * Dd + sc4);
        vreg1 = *(const bf16x4*)(vp + base + (size_t)(2 * r2v + 1) * Dd + sc4);
    };
    auto stash = [&](int buf) {
        *(bf16x8*)&Ks[buf][krow][ksc8] = kreg;
        const unsigned short* v0 = (const unsigned short*)&vreg0;
        const unsigned short* v1 = (const unsigned short*)&vreg1;
        #pragma unroll
        for (int j = 0; j < 4; j++) {
            int d = sc4 + j;
            int col = (r2v + 4 * ((d >> 3) & 7)) & 31;
            unsigned int word = (unsigned int)v0[j] | ((unsigned int)v1[j] << 16);
            VtW[buf][d * 36 + col] = word;
        }
    };

    const int NT = Tt / 64;
    ldkv(0);
    stash(0);
    ldkv(1);
    __syncthreads();   // buf0 ready

    for (int t = 0; t < NT; t++) {
        int cur = t & 1;
        // QK^T swapped from buf[cur]
        f32x4 s4[4];
        __builtin_amdgcn_s_setprio(1);
        #pragma unroll
        for (int c = 0; c < 4; c++) {
            int row = sgrow + (c & 1) * 32 + (c >> 1) * 4;
            s4[c] = (f32x4){0.f, 0.f, 0.f, 0.f};
            bf16x8 kb0 = *(const bf16x8*)&Ks[cur][row][g * 8];
            s4[c] = __builtin_amdgcn_mfma_f32_16x16x32_bf16(kb0, qa[0], s4[c], 0, 0, 0);
            bf16x8 kb1 = *(const bf16x8*)&Ks[cur][row][32 + g * 8];
            s4[c] = __builtin_amdgcn_mfma_f32_16x16x32_bf16(kb1, qa[1], s4[c], 0, 0, 0);
        }
        __builtin_amdgcn_s_setprio(0);

        // write next tile's regs into buf[cur^1]; issue t+2 global loads
        if (t + 1 < NT) stash(cur ^ 1);
        if (t + 2 < NT) ldkv(t + 2);

        // per-lane max over 16 scores (one q-row slice); defer-max (T13)
        float lm = fmaxf(fmaxf(fmaxf(s4[0][0], s4[0][1]), fmaxf(s4[0][2], s4[0][3])),
                         fmaxf(fmaxf(s4[1][0], s4[1][1]), fmaxf(s4[1][2], s4[1][3])));
        lm = fmaxf(lm, fmaxf(fmaxf(s4[2][0], s4[2][1]), fmaxf(s4[2][2], s4[2][3])));
        lm = fmaxf(lm, fmaxf(fmaxf(s4[3][0], s4[3][1]), fmaxf(s4[3][2], s4[3][3])));
        bool near = (lm - mrun <= 8.f);
        if (!__all((int)near)) {
            float tm = fmaxf(lm, __shfl_xor(lm, 16));
            tm = fmaxf(tm, __shfl_xor(tm, 32));
            float mnew = fmaxf(mrun, tm);
            float alpha = exp2f(mrun - mnew);
            mrun = mnew;
            lrun *= alpha;
            float ar[4];
            #pragma unroll
            for (int r = 0; r < 4; r++) ar[r] = __shfl(alpha, 20 * g + r);
            #pragma unroll
            for (int d2 = 0; d2 < 4; d2++)
                #pragma unroll
                for (int r = 0; r < 4; r++) oacc[d2][r] *= ar[r];
        }
        // P = exp2(s - m); lane-partial l; PV A-frags built in-lane
        float psum = 0.f;
        bf16x8 pa0, pa1;
        #pragma unroll
        for (int cc = 0; cc < 2; cc++)
            #pragma unroll
            for (int r = 0; r < 4; r++) {
                float e0 = exp2f(s4[2 * cc][r] - mrun);
                float e1 = exp2f(s4[2 * cc + 1][r] - mrun);
                psum += e0 + e1;
                pa0[cc * 4 + r] = (__bf16)e0;
                pa1[cc * 4 + r] = (__bf16)e1;
            }
        lrun += psum;

        __builtin_amdgcn_s_setprio(1);
        #pragma unroll
        for (int d2 = 0; d2 < 4; d2++) {
            int d = d2 * 16 + l15;
            int rot = ((2 * d2 + (l15 >> 3)) & 7) * 4;
            const unsigned int* vrow = VtW[cur] + d * 36;
            bf16x8 vb0 = *(const bf16x8*)(vrow + ((4 * g + rot) & 31));
            bf16x8 vb1 = *(const bf16x8*)(vrow + ((16 + 4 * g + rot) & 31));
            oacc[d2] = __builtin_amdgcn_mfma_f32_16x16x32_bf16(pa0, vb0, oacc[d2], 0, 0, 0);
            oacc[d2] = __builtin_amdgcn_mfma_f32_16x16x32_bf16(pa1, vb1, oacc[d2], 0, 0, 0);
        }
        __builtin_amdgcn_s_setprio(0);

        __syncthreads();   // single barrier per tile (dbuf invariant)
    }

    // total l per q-row (reduce the 4 g-slices), then fetch per-output-row
    lrun += __shfl_xor(lrun, 16);
    lrun += __shfl_xor(lrun, 32);
    float lr[4];
    #pragma unroll
    for (int r = 0; r < 4; r++) lr[r] = __shfl(lrun, 20 * g + r);

    __bf16* op = o + (size_t)b * Tt * Dd + (size_t)h * DHd;
    #pragma unroll
    for (int d2 = 0; d2 < 4; d2++)
        #pragma unroll
        for (int r = 0; r < 4; r++)
            op[(size_t)(qbase + w * 16 + g * 4 + r) * Dd + d2 * 16 + l15] =
                (__bf16)(oacc[d2][r] / lr[r]);
}

// segment scan + fused count atomics (run-length aggregated)
__global__ void seg_scan_kernel(const int* __restrict__ tokens, int* __restrict__ segid,
                                float* __restrict__ cnt) {
    int b = blockIdx.x;
    int tid = threadIdx.x;
    const int* trow = tokens + (size_t)b * Tt;
    int base = tid * 8;
    int inc[8];
    int run = 0;
    #pragma unroll
    for (int i = 0; i < 8; i++) {
        int tk = trow[base + i];
        tk = tk < 0 ? 0 : (tk > 255 ? 255 : tk);
        run += is_sep(tk);
        inc[i] = run;
    }
    __shared__ int part[256];
    part[tid] = run;
    __syncthreads();
    for (int off = 1; off < 256; off <<= 1) {
        int vv = (tid >= off) ? part[tid - off] : 0;
        __syncthreads();
        part[tid] += vv;
        __syncthreads();
    }
    int exc = part[tid] - run;
    int sid[8];
    #pragma unroll
    for (int i = 0; i < 8; i++) {
        sid[i] = exc + inc[i] + b * (Tt + 1);
        segid[(size_t)b * Tt + base + i] = sid[i];
    }
    int curid = sid[0];
    float c = 1.0f;
    #pragma unroll
    for (int i = 1; i < 8; i++) {
        if (sid[i] == curid) c += 1.0f;
        else { atomicAdd(&cnt[curid], c); curid = sid[i]; c = 1.0f; }
    }
    atomicAdd(&cnt[curid], c);
}

__global__ void seg_accum_kernel(const float* __restrict__ h, const int* __restrict__ segid,
                                 float* __restrict__ segsum) {
    size_t idx = (size_t)blockIdx.x * blockDim.x + threadIdx.x;
    if (idx >= BTD) return;
    size_t row = idx >> 9;
    int d = idx & 511;
    atomicAdd(&segsum[(size_t)segid[row] * Dd + d], h[idx]);
}

__global__ void seg_final_kernel(const float* __restrict__ h, const float* __restrict__ segsum,
                                 const float* __restrict__ cnt, const int* __restrict__ segid,
                                 float* __restrict__ out) {
    size_t idx = (size_t)blockIdx.x * blockDim.x + threadIdx.x;
    if (idx >= BTD) return;
    size_t row = idx >> 9;
    int d = idx & 511;
    int s = segid[row];
    float mean = segsum[(size_t)s * Dd + d] / fmaxf(cnt[s], 1.0f);
    out[idx] = 0.5f * h[idx] + 0.5f * mean;
}

extern "C" void kernel_launch(void* const* d_in, const int* in_sizes, int n_in,
                              void* d_out, int out_size, void* d_ws, size_t ws_size,
                              hipStream_t stream) {
    const int*   tokens       = (const int*)d_in[0];
    const float* embedw       = (const float*)d_in[1];
    const float* attn_norm_w  = (const float*)d_in[2];
    const float* wq           = (const float*)d_in[3];
    const float* wk           = (const float*)d_in[4];
    const float* wv           = (const float*)d_in[5];
    const float* wo           = (const float*)d_in[6];
    const float* ffn_norm_w   = (const float*)d_in[7];
    const float* w1           = (const float*)d_in[8];
    const float* w2           = (const float*)d_in[9];
    const float* w3           = (const float*)d_in[10];
    const float* final_norm_w = (const float*)d_in[11];
    float* out = (float*)d_out;
    float* ws  = (float*)d_ws;

    float*  x    = ws;
    __bf16* qkvo = (__bf16*)(ws + BTD);
    __bf16* qb   = qkvo;
    __bf16* kb   = qkvo + BTD;
    __bf16* vb   = qkvo + 2 * BTD;
    __bf16* obuf = qkvo + 3 * BTD;
    __bf16* gbuf = qkvo;                    // overlay (FFN phase)
    float*  segsum = ws + BTD;              // overlay (qkvo dead after last w2)
    __bf16* xnb  = (__bf16*)(ws + 3 * BTD);
    __bf16* wb   = (__bf16*)(ws + 3 * BTD + BTD / 2);
    float*  cosb = ws + 3 * BTD + BTD / 2 + 8388608;
    float*  sinb = cosb + (size_t)Tt * 32;
    float*  segcnt = sinb + (size_t)Tt * 32;
    int*    segid  = (int*)(segcnt + Bq * (Tt + 1));

    __bf16* wqkvb = wb;                     // [L][1536][512]
    __bf16* wob = wb + 3145728;             // wo|w1|w3|w2 contiguous from here
    __bf16* w1b = wb + 4194304;
    __bf16* w3b = wb + 8388608;
    __bf16* w2b = wb + 12582912;

    cvt_qkv_kernel<<<1536, 256, 0, stream>>>(wq, wk, wv, wqkvb);
    cvt_w_kernel<<<6656, 256, 0, stream>>>(wo, w1, w3, w2, wob);

    embed_kernel<<<(int)((BTD / 4 + 255) / 256), 256, 0, stream>>>(tokens, embedw, x);
    rope_table_kernel<<<(Tt * 32 + 255) / 256, 256, 0, stream>>>(cosb, sinb);

    dim3 gqkv(12, 64);    // N=1536, 128x128 tiles
    dim3 g64(8, 128);     // N=512, 64x64 tiles
    dim3 gs(16, 64);      // N=2048, 128x128 tiles
    dim3 ga(512);         // attn: 512 blocks x 512 threads, XCD remap in-kernel
    int grms = BT / 4;    // wave-per-row rmsnorm

    for (int l = 0; l < Ll; l++) {
        size_t oDD = (size_t)l * Dd * Dd;
        size_t oHD = (size_t)l * HIDN * Dd;
        rmsnorm_bf16_kernel<<<grms, 256, 0, stream>>>(x, attn_norm_w + (size_t)l * Dd, xnb);
        gemm_bt_mfma<2><<<gqkv, 256, 0, stream>>>(xnb, wqkvb + (size_t)l * 786432, nullptr, qb,
                                                  1536, Dd, cosb, sinb);
        attn_mfma_kernel<<<ga, 512, 0, stream>>>(qb, kb, vb, obuf);
        gemm_bt_mfma64<<<g64, 256, 0, stream>>>(obuf, wob + oDD, x, x, Dd, Dd);
        rmsnorm_bf16_kernel<<<grms, 256, 0, stream>>>(x, ffn_norm_w + (size_t)l * Dd, xnb);
        gemm_swiglu_mfma<<<gs, 256, 0, stream>>>(xnb, w1b + oHD, w3b + oHD, gbuf, HIDN, Dd);
        gemm_bt_mfma64<<<g64, 256, 0, stream>>>(gbuf, w2b + oHD, x, x, Dd, HIDN);
    }

    // tail: in-place final norm, then segment pooling
    rmsnorm_inplace_kernel<<<grms, 256, 0, stream>>>(x, final_norm_w);
    hipMemsetAsync(segsum, 0, (size_t)Bq * (Tt + 1) * Dd * sizeof(float), stream);
    hipMemsetAsync(segcnt, 0, (size_t)Bq * (Tt + 1) * sizeof(float), stream);
    seg_scan_kernel<<<Bq, 256, 0, stream>>>(tokens, segid, segcnt);
    seg_accum_kernel<<<(int)((BTD + 255) / 256), 256, 0, stream>>>(x, segid, segsum);
    seg_final_kernel<<<(int)((BTD + 255) / 256), 256, 0, stream>>>(x, segsum, segcnt, segid, out);
}